// Round 10
// baseline (439.981 us; speedup 1.0000x reference)
//
#include <hip/hip_runtime.h>

#define TN 64
#define NB 2
#define CH 8
#define HH 128
#define WW 128
#define HW (HH*WW)        // 16384
#define CHW (CH*HW)       // 131072
#define NCHW (NB*CHW)     // 262144
#define ST_X 64           // t stride per x step
#define ST_Y (WW*ST_X)    // 8192
#define ST_C (HH*ST_Y)    // 1048576

// ---------------------------------------------------------------------------
// All tensors live in the t-minor layout [n][c][y][x][t] (= input layout).
// ---------------------------------------------------------------------------

// K1: psp1 alpha filter (tau=1). One thread per (n,c,h,w); t-minor in/out.
__global__ __launch_bounds__(256) void k_psp1(const float* __restrict__ x,
                                              float* __restrict__ psp1) {
    int e = blockIdx.x * blockDim.x + threadIdx.x;
    const float d1 = 0.36787944117144233f;  // exp(-1)
    const float c1 = 2.7182818284590452f;   // e * Ts/tau * Ts
    float P = 0.f, Q = 0.f;
    const float4* xe = reinterpret_cast<const float4*>(x + (size_t)e * TN);
    float4* oe = reinterpret_cast<float4*>(psp1 + (size_t)e * TN);
    #pragma unroll
    for (int t4 = 0; t4 < TN / 4; ++t4) {
        float4 xv = xe[t4];
        float ys[4];
        float xs[4] = {xv.x, xv.y, xv.z, xv.w};
        #pragma unroll
        for (int j = 0; j < 4; ++j) {
            Q = d1 * (Q + P);
            P = d1 * P + xs[j];
            ys[j] = c1 * Q;
        }
        oe[t4] = make_float4(ys[0], ys[1], ys[2], ys[3]);
    }
}

// ---------------------------------------------------------------------------
// K2: conv1 5x5 pad=2, t-minor, LDS-free. Thread = (y, x, t-quad).
// Each float4 load along t feeds 32 FMAs with SGPR weights. Spatial reuse
// via L1/L2. Interior blocks take a check-free fast path (uniform branch).
// ---------------------------------------------------------------------------
__global__ __launch_bounds__(256) void k_conv1(const float* __restrict__ in,
                                               const float* __restrict__ w1,
                                               float* __restrict__ outp) {
    const int tid = threadIdx.x;
    const int tq = tid & 15;                 // t-quad: t0 = 4*tq
    const int xi = tid >> 4;                 // 0..15
    const int x  = blockIdx.x * 16 + xi;
    const int y  = blockIdx.y;
    const int n  = blockIdx.z;
    const int t0 = tq * 4;
    const float* pn = in + (size_t)n * (CH * ST_C) + t0;

    float acc[CH][4];
    #pragma unroll
    for (int co = 0; co < CH; ++co)
        #pragma unroll
        for (int j = 0; j < 4; ++j) acc[co][j] = 0.f;

    const bool interior = (y >= 2) && (y <= HH - 3) &&
                          (blockIdx.x >= 1) && (blockIdx.x <= 6);
    if (interior) {
        for (int ci = 0; ci < CH; ++ci) {
            const float* cb = pn + ci * ST_C + (y - 2) * ST_Y + (x - 2) * ST_X;
            #pragma unroll
            for (int ky = 0; ky < 5; ++ky) {
                const float* rb = cb + ky * ST_Y;
                #pragma unroll
                for (int kx = 0; kx < 5; ++kx) {
                    float4 f = *reinterpret_cast<const float4*>(rb + kx * ST_X);
                    float fs[4] = {f.x, f.y, f.z, f.w};
                    #pragma unroll
                    for (int co = 0; co < CH; ++co) {
                        float wv = w1[(co * CH + ci) * 25 + ky * 5 + kx];
                        #pragma unroll
                        for (int j = 0; j < 4; ++j)
                            acc[co][j] = fmaf(wv, fs[j], acc[co][j]);
                    }
                }
            }
        }
    } else {
        for (int ci = 0; ci < CH; ++ci) {
            const float* cb = pn + ci * ST_C;
            #pragma unroll
            for (int ky = 0; ky < 5; ++ky) {
                int yy = y + ky - 2;
                bool oky = (unsigned)yy < (unsigned)HH;
                const float* rb = cb + (oky ? yy : 0) * ST_Y;
                #pragma unroll
                for (int kx = 0; kx < 5; ++kx) {
                    int xx = x + kx - 2;
                    bool ok = oky && ((unsigned)xx < (unsigned)WW);
                    float4 f = *reinterpret_cast<const float4*>(rb + (ok ? xx : 0) * ST_X);
                    float fs[4] = {ok ? f.x : 0.f, ok ? f.y : 0.f,
                                   ok ? f.z : 0.f, ok ? f.w : 0.f};
                    #pragma unroll
                    for (int co = 0; co < CH; ++co) {
                        float wv = w1[(co * CH + ci) * 25 + ky * 5 + kx];
                        #pragma unroll
                        for (int j = 0; j < 4; ++j)
                            acc[co][j] = fmaf(wv, fs[j], acc[co][j]);
                    }
                }
            }
        }
    }

    float* ob = outp + (size_t)n * (CH * ST_C) + y * ST_Y + x * ST_X + t0;
    #pragma unroll
    for (int co = 0; co < CH; ++co)
        *reinterpret_cast<float4*>(ob + co * ST_C) =
            make_float4(acc[co][0], acc[co][1], acc[co][2], acc[co][3]);
}

// ---------------------------------------------------------------------------
// K3: LIF1 (theta=30, tauRef=1) + psp2 (tau=2), fused pointwise, t-minor.
// ---------------------------------------------------------------------------
__global__ __launch_bounds__(256) void k_lif1_psp2(const float* __restrict__ u1,
                                                   float* __restrict__ psp2) {
    int e = blockIdx.x * blockDim.x + threadIdx.x;
    const float dr = 0.36787944117144233f;  // exp(-1)
    const float rg = 81.54845485377136f;    // 30*e
    const float th = 30.f;
    const float d2 = 0.60653065971263342f;  // exp(-0.5)
    const float c2 = 1.35914091422952262f;  // e/2
    float Pr = 0.f, Qr = 0.f, P2 = 0.f, Q2 = 0.f;
    const float4* ue = reinterpret_cast<const float4*>(u1 + (size_t)e * TN);
    float4* oe = reinterpret_cast<float4*>(psp2 + (size_t)e * TN);
    #pragma unroll
    for (int t4 = 0; t4 < TN / 4; ++t4) {
        float4 uv = ue[t4];
        float us[4] = {uv.x, uv.y, uv.z, uv.w};
        float ys[4];
        #pragma unroll
        for (int j = 0; j < 4; ++j) {
            Qr = dr * (Qr + Pr);
            float s = (us[j] - rg * Qr >= th) ? 1.0f : 0.0f;
            Pr = dr * Pr + s;
            Q2 = d2 * (Q2 + P2);
            P2 = d2 * P2 + s;
            ys[j] = c2 * Q2;
        }
        oe[t4] = make_float4(ys[0], ys[1], ys[2], ys[3]);
    }
}

// ---------------------------------------------------------------------------
// K4: conv2 3x3 pad=1, t-minor, LDS-free. Same structure as K2.
// ---------------------------------------------------------------------------
__global__ __launch_bounds__(256) void k_conv2(const float* __restrict__ in,
                                               const float* __restrict__ w2,
                                               float* __restrict__ outp) {
    const int tid = threadIdx.x;
    const int tq = tid & 15;
    const int xi = tid >> 4;
    const int x  = blockIdx.x * 16 + xi;
    const int y  = blockIdx.y;
    const int n  = blockIdx.z;
    const int t0 = tq * 4;
    const float* pn = in + (size_t)n * (CH * ST_C) + t0;

    float acc[CH][4];
    #pragma unroll
    for (int co = 0; co < CH; ++co)
        #pragma unroll
        for (int j = 0; j < 4; ++j) acc[co][j] = 0.f;

    const bool interior = (y >= 1) && (y <= HH - 2) &&
                          (blockIdx.x >= 1) && (blockIdx.x <= 6);
    if (interior) {
        for (int ci = 0; ci < CH; ++ci) {
            const float* cb = pn + ci * ST_C + (y - 1) * ST_Y + (x - 1) * ST_X;
            #pragma unroll
            for (int ky = 0; ky < 3; ++ky) {
                const float* rb = cb + ky * ST_Y;
                #pragma unroll
                for (int kx = 0; kx < 3; ++kx) {
                    float4 f = *reinterpret_cast<const float4*>(rb + kx * ST_X);
                    float fs[4] = {f.x, f.y, f.z, f.w};
                    #pragma unroll
                    for (int co = 0; co < CH; ++co) {
                        float wv = w2[(co * CH + ci) * 9 + ky * 3 + kx];
                        #pragma unroll
                        for (int j = 0; j < 4; ++j)
                            acc[co][j] = fmaf(wv, fs[j], acc[co][j]);
                    }
                }
            }
        }
    } else {
        for (int ci = 0; ci < CH; ++ci) {
            const float* cb = pn + ci * ST_C;
            #pragma unroll
            for (int ky = 0; ky < 3; ++ky) {
                int yy = y + ky - 1;
                bool oky = (unsigned)yy < (unsigned)HH;
                const float* rb = cb + (oky ? yy : 0) * ST_Y;
                #pragma unroll
                for (int kx = 0; kx < 3; ++kx) {
                    int xx = x + kx - 1;
                    bool ok = oky && ((unsigned)xx < (unsigned)WW);
                    float4 f = *reinterpret_cast<const float4*>(rb + (ok ? xx : 0) * ST_X);
                    float fs[4] = {ok ? f.x : 0.f, ok ? f.y : 0.f,
                                   ok ? f.z : 0.f, ok ? f.w : 0.f};
                    #pragma unroll
                    for (int co = 0; co < CH; ++co) {
                        float wv = w2[(co * CH + ci) * 9 + ky * 3 + kx];
                        #pragma unroll
                        for (int j = 0; j < 4; ++j)
                            acc[co][j] = fmaf(wv, fs[j], acc[co][j]);
                    }
                }
            }
        }
    }

    float* ob = outp + (size_t)n * (CH * ST_C) + y * ST_Y + x * ST_X + t0;
    #pragma unroll
    for (int co = 0; co < CH; ++co)
        *reinterpret_cast<float4*>(ob + co * ST_C) =
            make_float4(acc[co][0], acc[co][1], acc[co][2], acc[co][3]);
}

// ---------------------------------------------------------------------------
// K5: LIF2 (theta=50, tauRef=2), t-minor in/out; streams float4 directly.
// ---------------------------------------------------------------------------
__global__ __launch_bounds__(256) void k_lif2(const float* __restrict__ u2,
                                              float* __restrict__ outp) {
    int e = blockIdx.x * blockDim.x + threadIdx.x;
    const float dr = 0.60653065971263342f;  // exp(-0.5)
    const float rg = 67.95704571147613f;    // 25*e
    const float th = 50.f;
    float Pr = 0.f, Qr = 0.f;
    const float4* ue = reinterpret_cast<const float4*>(u2 + (size_t)e * TN);
    float4* oe = reinterpret_cast<float4*>(outp + (size_t)e * TN);
    #pragma unroll
    for (int t4 = 0; t4 < TN / 4; ++t4) {
        float4 uv = ue[t4];
        float us[4] = {uv.x, uv.y, uv.z, uv.w};
        float ss[4];
        #pragma unroll
        for (int j = 0; j < 4; ++j) {
            Qr = dr * (Qr + Pr);
            float s = (us[j] - rg * Qr >= th) ? 1.0f : 0.0f;
            Pr = dr * Pr + s;
            ss[j] = s;
        }
        oe[t4] = make_float4(ss[0], ss[1], ss[2], ss[3]);
    }
}

// ---------------------------------------------------------------------------
extern "C" void kernel_launch(void* const* d_in, const int* in_sizes, int n_in,
                              void* d_out, int out_size, void* d_ws, size_t ws_size,
                              hipStream_t stream) {
    const float* x  = (const float*)d_in[0];   // [2,8,128,128,64]
    const float* w1 = (const float*)d_in[1];   // [8,8,5,5]
    const float* w2 = (const float*)d_in[2];   // [8,8,3,3]
    float* out = (float*)d_out;                // [2,8,128,128,64]

    float* bufA = (float*)d_ws;                       // psp1, then psp2
    float* bufB = bufA + (size_t)TN * NCHW;           // u1,   then u2

    dim3 blk(256);
    dim3 grd_pt(NCHW / 256);          // 1024 blocks, pointwise kernels
    dim3 grd_cv(8, HH, NB);           // 8 x-tiles x 128 rows x 2 batch

    k_psp1<<<grd_pt, blk, 0, stream>>>(x, bufA);
    k_conv1<<<grd_cv, blk, 0, stream>>>(bufA, w1, bufB);
    k_lif1_psp2<<<grd_pt, blk, 0, stream>>>(bufB, bufA);
    k_conv2<<<grd_cv, blk, 0, stream>>>(bufA, w2, bufB);
    k_lif2<<<grd_pt, blk, 0, stream>>>(bufB, out);
}

// Round 11
// 194.499 us; speedup vs baseline: 2.2621x; 2.2621x over previous
//
#include <hip/hip_runtime.h>

#define TN 64
#define NB 2
#define CH 8
#define HH 128
#define WW 128
#define HW (HH*WW)        // 16384
#define CHW (CH*HW)       // 131072
#define NCHW (NB*CHW)     // 262144

// ---------------------------------------------------------------------------
// K1: psp1 alpha filter (tau=1). One thread per (n,c,h,w) element.
// Reads t-minor input (float4 along t), writes t-major planes [t][n][c][h][w].
// ---------------------------------------------------------------------------
__global__ __launch_bounds__(256) void k_psp1(const float* __restrict__ x,
                                              float* __restrict__ psp1) {
    int e = blockIdx.x * blockDim.x + threadIdx.x;
    if (e >= NCHW) return;
    const float d1 = 0.36787944117144233f;  // exp(-1)
    const float c1 = 2.7182818284590452f;   // e * Ts/tau * Ts
    float P = 0.f, Q = 0.f;
    const float4* xe = reinterpret_cast<const float4*>(x + (size_t)e * TN);
    #pragma unroll
    for (int t4 = 0; t4 < TN / 4; ++t4) {
        float4 xv = xe[t4];
        float xs[4] = {xv.x, xv.y, xv.z, xv.w};
        #pragma unroll
        for (int j = 0; j < 4; ++j) {
            Q = d1 * (Q + P);
            P = d1 * P + xs[j];
            psp1[(size_t)(t4 * 4 + j) * NCHW + e] = c1 * Q;
        }
    }
}

// ---------------------------------------------------------------------------
// K2: conv1 5x5 pad=2. Block = 256 thr = 8 rows x 32 lanes x 4 px.
// Single-channel double-buffered phases: LDS [2buf][12][136] = 13.1 KB,
// 8 phases, 1 barrier each. goff[] hoisted; va[7] reg prefetch overlaps
// next channel's HBM latency with current channel's FMAs.
// Weights via SMEM (uniform s_load -> SGPR, free FMA operand).
// (256,4) bounds: proven spill-free region (R5); R9's (256,6) spilled.
// ---------------------------------------------------------------------------
__global__ __launch_bounds__(256, 4) void k_conv1(const float* __restrict__ in,
                                                  const float* __restrict__ w1,
                                                  float* __restrict__ outp) {
    __shared__ __align__(16) float tile[2][12][136];
    const int img = blockIdx.y;                 // t*NB + n, 0..127
    const int h0 = blockIdx.x * 8;              // 16 y-tiles
    const int tid = threadIdx.x;
    const int yi = tid >> 5;                    // 0..7
    const int x0 = (tid & 31) * 4;              // 0..124
    const float* base = in + (size_t)img * CHW;

    // staging offsets: computed ONCE, reused for all 8 channel phases
    int goff[7];                                // 12*136 = 1632 slots
    #pragma unroll
    for (int k = 0; k < 7; ++k) {
        int idx = tid + (k << 8);
        int r = idx / 136;
        int c = idx - r * 136;
        int gh = h0 + r - 2, gw = c - 2;
        bool ok = (idx < 1632) && (gh >= 0) && (gh < HH) && (gw >= 0) && (gw < WW);
        goff[k] = ok ? (gh * WW + gw) : -1;
    }

    float va[7];
    #pragma unroll
    for (int k = 0; k < 7; ++k) {               // prefetch channel 0
        int g = goff[k];
        int gc = g < 0 ? 0 : g;
        float t0 = base[gc];
        va[k] = g < 0 ? 0.f : t0;
    }

    float acc[CH][4];
    #pragma unroll
    for (int co = 0; co < CH; ++co)
        #pragma unroll
        for (int xo = 0; xo < 4; ++xo) acc[co][xo] = 0.f;

    for (int ci = 0; ci < CH; ++ci) {
        float* dst = &tile[ci & 1][0][0];
        #pragma unroll
        for (int k = 0; k < 7; ++k) {
            int idx = tid + (k << 8);
            if (k < 6 || idx < 1632) dst[idx] = va[k];
        }
        if (ci < 7) {                            // prefetch next channel
            const float* nb = base + (size_t)(ci + 1) * HW;
            #pragma unroll
            for (int k = 0; k < 7; ++k) {
                int g = goff[k];
                int gc = g < 0 ? 0 : g;
                float t0 = nb[gc];
                va[k] = g < 0 ? 0.f : t0;
            }
        }
        __syncthreads();                         // staged data visible

        const float* chp = &tile[ci & 1][0][0];
        #pragma unroll
        for (int ky = 0; ky < 5; ++ky) {
            const float4* rp =
                reinterpret_cast<const float4*>(chp + (yi + ky) * 136 + x0);
            float4 A = rp[0], B = rp[1];
            float f[8] = {A.x, A.y, A.z, A.w, B.x, B.y, B.z, B.w};
            #pragma unroll
            for (int co = 0; co < CH; ++co) {
                const float* wp = w1 + (co * CH + ci) * 25 + ky * 5;
                #pragma unroll
                for (int kx = 0; kx < 5; ++kx) {
                    float wv = wp[kx];
                    #pragma unroll
                    for (int xo = 0; xo < 4; ++xo)
                        acc[co][xo] = fmaf(wv, f[kx + xo], acc[co][xo]);
                }
            }
        }
        // no trailing barrier: next phase writes the OTHER LDS buffer;
        // re-write of THIS buffer is 2 barriers away.
    }

    float* ob = outp + (size_t)img * CHW + (h0 + yi) * WW + x0;
    #pragma unroll
    for (int co = 0; co < CH; ++co)
        *reinterpret_cast<float4*>(ob + co * HW) =
            make_float4(acc[co][0], acc[co][1], acc[co][2], acc[co][3]);
}

// ---------------------------------------------------------------------------
// K3: LIF1 (theta=30, tauRef=1) + psp2 (tau=2), fused pointwise.
// float2-vectorized: 2 independent IIR chains per thread (ILP), half the
// VMEM instructions. t-major planes on both sides -> coalesced float2.
// ---------------------------------------------------------------------------
__global__ __launch_bounds__(256) void k_lif1_psp2(const float* __restrict__ u1,
                                                   float* __restrict__ psp2) {
    int e2 = blockIdx.x * blockDim.x + threadIdx.x;   // 0..NCHW/2-1
    if (e2 >= NCHW / 2) return;
    const float dr = 0.36787944117144233f;  // exp(-1)
    const float rg = 81.54845485377136f;    // 30*e
    const float th = 30.f;
    const float d2 = 0.60653065971263342f;  // exp(-0.5)
    const float c2 = 1.35914091422952262f;  // e/2
    float Pr0 = 0.f, Qr0 = 0.f, P20 = 0.f, Q20 = 0.f;
    float Pr1 = 0.f, Qr1 = 0.f, P21 = 0.f, Q21 = 0.f;
    const float2* ue = reinterpret_cast<const float2*>(u1);
    float2* oe = reinterpret_cast<float2*>(psp2);
    #pragma unroll 8
    for (int t = 0; t < TN; ++t) {
        float2 uv = ue[(size_t)t * (NCHW / 2) + e2];
        Qr0 = dr * (Qr0 + Pr0);
        float s0 = (uv.x - rg * Qr0 >= th) ? 1.0f : 0.0f;
        Pr0 = dr * Pr0 + s0;
        Q20 = d2 * (Q20 + P20);
        P20 = d2 * P20 + s0;
        Qr1 = dr * (Qr1 + Pr1);
        float s1 = (uv.y - rg * Qr1 >= th) ? 1.0f : 0.0f;
        Pr1 = dr * Pr1 + s1;
        Q21 = d2 * (Q21 + P21);
        P21 = d2 * P21 + s1;
        oe[(size_t)t * (NCHW / 2) + e2] = make_float2(c2 * Q20, c2 * Q21);
    }
}

// ---------------------------------------------------------------------------
// K4: conv2 3x3 pad=1. Same single-channel dbuf structure as K2.
// LDS [2][10][136] = 10.9 KB; per (ci,ky): 2 ds_read_b128 -> 96 FMA.
// ---------------------------------------------------------------------------
__global__ __launch_bounds__(256, 4) void k_conv2(const float* __restrict__ in,
                                                  const float* __restrict__ w2,
                                                  float* __restrict__ outp) {
    __shared__ __align__(16) float tile[2][10][136];
    const int img = blockIdx.y;
    const int h0 = blockIdx.x * 8;
    const int tid = threadIdx.x;
    const int yi = tid >> 5;
    const int x0 = (tid & 31) * 4;
    const float* base = in + (size_t)img * CHW;

    int goff[6];                                // 10*136 = 1360 slots
    #pragma unroll
    for (int k = 0; k < 6; ++k) {
        int idx = tid + (k << 8);
        int r = idx / 136;
        int c = idx - r * 136;
        int gh = h0 + r - 1, gw = c - 1;
        bool ok = (idx < 1360) && (gh >= 0) && (gh < HH) && (gw >= 0) && (gw < WW);
        goff[k] = ok ? (gh * WW + gw) : -1;
    }

    float va[6];
    #pragma unroll
    for (int k = 0; k < 6; ++k) {
        int g = goff[k];
        int gc = g < 0 ? 0 : g;
        float t0 = base[gc];
        va[k] = g < 0 ? 0.f : t0;
    }

    float acc[CH][4];
    #pragma unroll
    for (int co = 0; co < CH; ++co)
        #pragma unroll
        for (int xo = 0; xo < 4; ++xo) acc[co][xo] = 0.f;

    for (int ci = 0; ci < CH; ++ci) {
        float* dst = &tile[ci & 1][0][0];
        #pragma unroll
        for (int k = 0; k < 6; ++k) {
            int idx = tid + (k << 8);
            if (k < 5 || idx < 1360) dst[idx] = va[k];
        }
        if (ci < 7) {
            const float* nb = base + (size_t)(ci + 1) * HW;
            #pragma unroll
            for (int k = 0; k < 6; ++k) {
                int g = goff[k];
                int gc = g < 0 ? 0 : g;
                float t0 = nb[gc];
                va[k] = g < 0 ? 0.f : t0;
            }
        }
        __syncthreads();

        const float* chp = &tile[ci & 1][0][0];
        #pragma unroll
        for (int ky = 0; ky < 3; ++ky) {
            const float4* rp =
                reinterpret_cast<const float4*>(chp + (yi + ky) * 136 + x0);
            float4 A = rp[0], B = rp[1];
            float f[8] = {A.x, A.y, A.z, A.w, B.x, B.y, B.z, B.w};
            #pragma unroll
            for (int co = 0; co < CH; ++co) {
                const float* wp = w2 + (co * CH + ci) * 9 + ky * 3;
                #pragma unroll
                for (int kx = 0; kx < 3; ++kx) {
                    float wv = wp[kx];
                    #pragma unroll
                    for (int xo = 0; xo < 4; ++xo)
                        acc[co][xo] = fmaf(wv, f[kx + xo], acc[co][xo]);
                }
            }
        }
    }

    float* ob = outp + (size_t)img * CHW + (h0 + yi) * WW + x0;
    #pragma unroll
    for (int co = 0; co < CH; ++co)
        *reinterpret_cast<float4*>(ob + co * HW) =
            make_float4(acc[co][0], acc[co][1], acc[co][2], acc[co][3]);
}

// ---------------------------------------------------------------------------
// K5: LIF2 (theta=50, tauRef=2). Buffers 64 spikes in registers, writes
// output [N,C,H,W,T] (t-contiguous per thread) as float4.
// ---------------------------------------------------------------------------
__global__ __launch_bounds__(256) void k_lif2(const float* __restrict__ u2,
                                              float* __restrict__ outp) {
    int e = blockIdx.x * blockDim.x + threadIdx.x;
    if (e >= NCHW) return;
    const float dr = 0.60653065971263342f;  // exp(-0.5)
    const float rg = 67.95704571147613f;    // 25*e
    const float th = 50.f;
    float Pr = 0.f, Qr = 0.f;
    float sv[TN];
    #pragma unroll
    for (int t = 0; t < TN; ++t) {
        Qr = dr * (Qr + Pr);
        float u = u2[(size_t)t * NCHW + e];
        float s = (u - rg * Qr >= th) ? 1.0f : 0.0f;
        Pr = dr * Pr + s;
        sv[t] = s;
    }
    float4* o = reinterpret_cast<float4*>(outp + (size_t)e * TN);
    #pragma unroll
    for (int i = 0; i < TN / 4; ++i)
        o[i] = make_float4(sv[4 * i], sv[4 * i + 1], sv[4 * i + 2], sv[4 * i + 3]);
}

// ---------------------------------------------------------------------------
extern "C" void kernel_launch(void* const* d_in, const int* in_sizes, int n_in,
                              void* d_out, int out_size, void* d_ws, size_t ws_size,
                              hipStream_t stream) {
    const float* x  = (const float*)d_in[0];   // [2,8,128,128,64]
    const float* w1 = (const float*)d_in[1];   // [8,8,5,5]
    const float* w2 = (const float*)d_in[2];   // [8,8,3,3]
    float* out = (float*)d_out;                // [2,8,128,128,64]

    float* bufA = (float*)d_ws;                       // psp1, then psp2
    float* bufB = bufA + (size_t)TN * NCHW;           // u1,   then u2

    dim3 blk(256);
    dim3 grd_pt(NCHW / 256);          // 1024 blocks
    dim3 grd_pt2(NCHW / 512);         // 512 blocks (float2 kernel)
    dim3 grd_cv(16, TN * NB);         // 16 row-tiles (8 rows) x 128 images

    k_psp1<<<grd_pt, blk, 0, stream>>>(x, bufA);
    k_conv1<<<grd_cv, blk, 0, stream>>>(bufA, w1, bufB);
    k_lif1_psp2<<<grd_pt2, blk, 0, stream>>>(bufB, bufA);
    k_conv2<<<grd_cv, blk, 0, stream>>>(bufA, w2, bufB);
    k_lif2<<<grd_pt, blk, 0, stream>>>(bufB, out);
}

// Round 12
// 180.846 us; speedup vs baseline: 2.4329x; 1.0755x over previous
//
#include <hip/hip_runtime.h>

#define TN 64
#define NB 2
#define CH 8
#define HH 128
#define WW 128
#define HW (HH*WW)        // 16384
#define CHW (CH*HW)       // 131072
#define NCHW (NB*CHW)     // 262144

// ---------------------------------------------------------------------------
// Pipeline (uses conv∘alpha = alpha∘conv, both linear, disjoint axes):
//   xT = transpose(x) as u8          [t][n][c][h][w]   (x is binary spikes)
//   v1 = conv1(xT)                   f32 t-major
//   s1 = LIF1(alpha1(v1))  as u8     (commuted: alpha1 after conv1)
//   v2 = conv2(s1)                   f32 t-major
//   out = LIF2(alpha2(v2))           t-minor [n][c][h][w][t]
// ---------------------------------------------------------------------------

// K0: transpose x [n,c,h,w,t] f32(binary) -> xT [t*NB+n][c][h][w] u8.
// LDS-staged: 256 e x 64 t tile; packed uchar4 writes (256B/wave-inst).
__global__ __launch_bounds__(256) void k_tr(const float* __restrict__ x,
                                            unsigned char* __restrict__ xT) {
    __shared__ unsigned char lds[256 * 68];          // [e][68B] pad: 17 words/row
    const int tid = threadIdx.x;
    const size_t e0 = (size_t)blockIdx.x * 256;
    const float4* xb = reinterpret_cast<const float4*>(x + (e0 + tid) * TN);
    unsigned int* lds32 = reinterpret_cast<unsigned int*>(lds);
    #pragma unroll
    for (int k = 0; k < 16; ++k) {
        float4 v = xb[k];
        unsigned int p = ((unsigned)v.x) | (((unsigned)v.y) << 8) |
                         (((unsigned)v.z) << 16) | (((unsigned)v.w) << 24);
        lds32[tid * 17 + k] = p;                     // bank stride 17: conflict-free
    }
    __syncthreads();
    const int lane = tid & 63, w = tid >> 6;
    #pragma unroll
    for (int k = 0; k < 16; ++k) {
        int t = w * 16 + k;
        unsigned int b0 = lds[(4 * lane + 0) * 68 + t];
        unsigned int b1 = lds[(4 * lane + 1) * 68 + t];
        unsigned int b2 = lds[(4 * lane + 2) * 68 + t];
        unsigned int b3 = lds[(4 * lane + 3) * 68 + t];
        unsigned int p = b0 | (b1 << 8) | (b2 << 16) | (b3 << 24);
        *reinterpret_cast<unsigned int*>(xT + (size_t)t * NCHW + e0 + 4 * lane) = p;
    }
}

// ---------------------------------------------------------------------------
// K1: conv1 5x5 pad=2 on u8 input. R11's proven structure: 8 rows x 32 lanes
// x 4 px, single-channel dbuf LDS [2][12][136] = 13.1 KB, goff hoisted,
// reg prefetch, SMEM weights, (256,4) spill-free region.
// ---------------------------------------------------------------------------
__global__ __launch_bounds__(256, 4) void k_conv1(const unsigned char* __restrict__ in,
                                                  const float* __restrict__ w1,
                                                  float* __restrict__ outp) {
    __shared__ __align__(16) float tile[2][12][136];
    const int img = blockIdx.y;                 // t*NB + n, 0..127
    const int h0 = blockIdx.x * 8;              // 16 y-tiles
    const int tid = threadIdx.x;
    const int yi = tid >> 5;                    // 0..7
    const int x0 = (tid & 31) * 4;              // 0..124
    const unsigned char* base = in + (size_t)img * CHW;

    int goff[7];                                // 12*136 = 1632 slots
    #pragma unroll
    for (int k = 0; k < 7; ++k) {
        int idx = tid + (k << 8);
        int r = idx / 136;
        int c = idx - r * 136;
        int gh = h0 + r - 2, gw = c - 2;
        bool ok = (idx < 1632) && (gh >= 0) && (gh < HH) && (gw >= 0) && (gw < WW);
        goff[k] = ok ? (gh * WW + gw) : -1;
    }

    float va[7];
    #pragma unroll
    for (int k = 0; k < 7; ++k) {               // prefetch channel 0
        int g = goff[k];
        int gc = g < 0 ? 0 : g;
        float t0 = (float)base[gc];
        va[k] = g < 0 ? 0.f : t0;
    }

    float acc[CH][4];
    #pragma unroll
    for (int co = 0; co < CH; ++co)
        #pragma unroll
        for (int xo = 0; xo < 4; ++xo) acc[co][xo] = 0.f;

    for (int ci = 0; ci < CH; ++ci) {
        float* dst = &tile[ci & 1][0][0];
        #pragma unroll
        for (int k = 0; k < 7; ++k) {
            int idx = tid + (k << 8);
            if (k < 6 || idx < 1632) dst[idx] = va[k];
        }
        if (ci < 7) {                            // prefetch next channel
            const unsigned char* nb = base + (size_t)(ci + 1) * HW;
            #pragma unroll
            for (int k = 0; k < 7; ++k) {
                int g = goff[k];
                int gc = g < 0 ? 0 : g;
                float t0 = (float)nb[gc];
                va[k] = g < 0 ? 0.f : t0;
            }
        }
        __syncthreads();

        const float* chp = &tile[ci & 1][0][0];
        #pragma unroll
        for (int ky = 0; ky < 5; ++ky) {
            const float4* rp =
                reinterpret_cast<const float4*>(chp + (yi + ky) * 136 + x0);
            float4 A = rp[0], B = rp[1];
            float f[8] = {A.x, A.y, A.z, A.w, B.x, B.y, B.z, B.w};
            #pragma unroll
            for (int co = 0; co < CH; ++co) {
                const float* wp = w1 + (co * CH + ci) * 25 + ky * 5;
                #pragma unroll
                for (int kx = 0; kx < 5; ++kx) {
                    float wv = wp[kx];
                    #pragma unroll
                    for (int xo = 0; xo < 4; ++xo)
                        acc[co][xo] = fmaf(wv, f[kx + xo], acc[co][xo]);
                }
            }
        }
    }

    float* ob = outp + (size_t)img * CHW + (h0 + yi) * WW + x0;
    #pragma unroll
    for (int co = 0; co < CH; ++co)
        *reinterpret_cast<float4*>(ob + co * HW) =
            make_float4(acc[co][0], acc[co][1], acc[co][2], acc[co][3]);
}

// ---------------------------------------------------------------------------
// K2: fused alpha1 (tau=1) + LIF1 (theta=30, tauRef=1) -> s1 u8.
// float2-vectorized (2 IIR chains/thread). u1 = alpha1(v1) (commuted).
// ---------------------------------------------------------------------------
__global__ __launch_bounds__(256) void k_alif1(const float* __restrict__ v1,
                                               unsigned char* __restrict__ s1) {
    int e2 = blockIdx.x * blockDim.x + threadIdx.x;   // 0..NCHW/2-1
    if (e2 >= NCHW / 2) return;
    const float d1 = 0.36787944117144233f;  // exp(-1)
    const float c1 = 2.7182818284590452f;   // e
    const float dr = 0.36787944117144233f;  // exp(-1)
    const float rg = 81.54845485377136f;    // 30*e
    const float th = 30.f;
    float P0 = 0.f, Q0 = 0.f, Pr0 = 0.f, Qr0 = 0.f;
    float P1 = 0.f, Q1 = 0.f, Pr1 = 0.f, Qr1 = 0.f;
    const float2* ve = reinterpret_cast<const float2*>(v1);
    #pragma unroll 8
    for (int t = 0; t < TN; ++t) {
        float2 v = ve[(size_t)t * (NCHW / 2) + e2];
        Q0 = d1 * (Q0 + P0); P0 = d1 * P0 + v.x;
        Qr0 = dr * (Qr0 + Pr0);
        float s0 = (c1 * Q0 - rg * Qr0 >= th) ? 1.0f : 0.0f;
        Pr0 = dr * Pr0 + s0;
        Q1 = d1 * (Q1 + P1); P1 = d1 * P1 + v.y;
        Qr1 = dr * (Qr1 + Pr1);
        float s1v = (c1 * Q1 - rg * Qr1 >= th) ? 1.0f : 0.0f;
        Pr1 = dr * Pr1 + s1v;
        uchar2 o; o.x = (unsigned char)s0; o.y = (unsigned char)s1v;
        *reinterpret_cast<uchar2*>(s1 + (size_t)t * NCHW + 2 * e2) = o;
    }
}

// ---------------------------------------------------------------------------
// K3: conv2 3x3 pad=1 on u8 spikes. Same structure; LDS [2][10][136]=10.9 KB.
// ---------------------------------------------------------------------------
__global__ __launch_bounds__(256, 4) void k_conv2(const unsigned char* __restrict__ in,
                                                  const float* __restrict__ w2,
                                                  float* __restrict__ outp) {
    __shared__ __align__(16) float tile[2][10][136];
    const int img = blockIdx.y;
    const int h0 = blockIdx.x * 8;
    const int tid = threadIdx.x;
    const int yi = tid >> 5;
    const int x0 = (tid & 31) * 4;
    const unsigned char* base = in + (size_t)img * CHW;

    int goff[6];                                // 10*136 = 1360 slots
    #pragma unroll
    for (int k = 0; k < 6; ++k) {
        int idx = tid + (k << 8);
        int r = idx / 136;
        int c = idx - r * 136;
        int gh = h0 + r - 1, gw = c - 1;
        bool ok = (idx < 1360) && (gh >= 0) && (gh < HH) && (gw >= 0) && (gw < WW);
        goff[k] = ok ? (gh * WW + gw) : -1;
    }

    float va[6];
    #pragma unroll
    for (int k = 0; k < 6; ++k) {
        int g = goff[k];
        int gc = g < 0 ? 0 : g;
        float t0 = (float)base[gc];
        va[k] = g < 0 ? 0.f : t0;
    }

    float acc[CH][4];
    #pragma unroll
    for (int co = 0; co < CH; ++co)
        #pragma unroll
        for (int xo = 0; xo < 4; ++xo) acc[co][xo] = 0.f;

    for (int ci = 0; ci < CH; ++ci) {
        float* dst = &tile[ci & 1][0][0];
        #pragma unroll
        for (int k = 0; k < 6; ++k) {
            int idx = tid + (k << 8);
            if (k < 5 || idx < 1360) dst[idx] = va[k];
        }
        if (ci < 7) {
            const unsigned char* nb = base + (size_t)(ci + 1) * HW;
            #pragma unroll
            for (int k = 0; k < 6; ++k) {
                int g = goff[k];
                int gc = g < 0 ? 0 : g;
                float t0 = (float)nb[gc];
                va[k] = g < 0 ? 0.f : t0;
            }
        }
        __syncthreads();

        const float* chp = &tile[ci & 1][0][0];
        #pragma unroll
        for (int ky = 0; ky < 3; ++ky) {
            const float4* rp =
                reinterpret_cast<const float4*>(chp + (yi + ky) * 136 + x0);
            float4 A = rp[0], B = rp[1];
            float f[8] = {A.x, A.y, A.z, A.w, B.x, B.y, B.z, B.w};
            #pragma unroll
            for (int co = 0; co < CH; ++co) {
                const float* wp = w2 + (co * CH + ci) * 9 + ky * 3;
                #pragma unroll
                for (int kx = 0; kx < 3; ++kx) {
                    float wv = wp[kx];
                    #pragma unroll
                    for (int xo = 0; xo < 4; ++xo)
                        acc[co][xo] = fmaf(wv, f[kx + xo], acc[co][xo]);
                }
            }
        }
    }

    float* ob = outp + (size_t)img * CHW + (h0 + yi) * WW + x0;
    #pragma unroll
    for (int co = 0; co < CH; ++co)
        *reinterpret_cast<float4*>(ob + co * HW) =
            make_float4(acc[co][0], acc[co][1], acc[co][2], acc[co][3]);
}

// ---------------------------------------------------------------------------
// K4: fused alpha2 (tau=2) + LIF2 (theta=50, tauRef=2). u2 = alpha2(v2)
// (commuted). Buffers 64 spikes in regs, writes t-minor output as float4.
// ---------------------------------------------------------------------------
__global__ __launch_bounds__(256) void k_alif2(const float* __restrict__ v2,
                                               float* __restrict__ outp) {
    int e = blockIdx.x * blockDim.x + threadIdx.x;
    if (e >= NCHW) return;
    const float d2 = 0.60653065971263342f;  // exp(-0.5)
    const float c2 = 1.35914091422952262f;  // e/2
    const float dr = 0.60653065971263342f;  // exp(-0.5)
    const float rg = 67.95704571147613f;    // 25*e
    const float th = 50.f;
    float P = 0.f, Q = 0.f, Pr = 0.f, Qr = 0.f;
    float sv[TN];
    #pragma unroll
    for (int t = 0; t < TN; ++t) {
        Q = d2 * (Q + P);
        P = d2 * P + v2[(size_t)t * NCHW + e];
        Qr = dr * (Qr + Pr);
        float s = (c2 * Q - rg * Qr >= th) ? 1.0f : 0.0f;
        Pr = dr * Pr + s;
        sv[t] = s;
    }
    float4* o = reinterpret_cast<float4*>(outp + (size_t)e * TN);
    #pragma unroll
    for (int i = 0; i < TN / 4; ++i)
        o[i] = make_float4(sv[4 * i], sv[4 * i + 1], sv[4 * i + 2], sv[4 * i + 3]);
}

// ---------------------------------------------------------------------------
extern "C" void kernel_launch(void* const* d_in, const int* in_sizes, int n_in,
                              void* d_out, int out_size, void* d_ws, size_t ws_size,
                              hipStream_t stream) {
    const float* x  = (const float*)d_in[0];   // [2,8,128,128,64] binary
    const float* w1 = (const float*)d_in[1];   // [8,8,5,5]
    const float* w2 = (const float*)d_in[2];   // [8,8,3,3]
    float* out = (float*)d_out;                // [2,8,128,128,64]

    // workspace: v-buffer f32 64MB (v1 then v2) + xT u8 16MB + s1 u8 16MB
    float* vbuf = (float*)d_ws;
    unsigned char* xT = (unsigned char*)d_ws + (size_t)TN * NCHW * 4;
    unsigned char* s1 = xT + (size_t)TN * NCHW;

    dim3 blk(256);
    dim3 grd_pt(NCHW / 256);          // 1024 blocks
    dim3 grd_pt2(NCHW / 512);         // 512 blocks (float2 kernel)
    dim3 grd_cv(16, TN * NB);         // 16 row-tiles x 128 images

    k_tr<<<grd_pt, blk, 0, stream>>>(x, xT);
    k_conv1<<<grd_cv, blk, 0, stream>>>(xT, w1, vbuf);
    k_alif1<<<grd_pt2, blk, 0, stream>>>(vbuf, s1);
    k_conv2<<<grd_cv, blk, 0, stream>>>(s1, w2, vbuf);
    k_alif2<<<grd_pt, blk, 0, stream>>>(vbuf, out);
}

// Round 13
// 178.936 us; speedup vs baseline: 2.4589x; 1.0107x over previous
//
#include <hip/hip_runtime.h>

#define TN 64
#define NB 2
#define CH 8
#define HH 128
#define WW 128
#define HW (HH*WW)        // 16384
#define CHW (CH*HW)       // 131072
#define NCHW (NB*CHW)     // 262144

// ---------------------------------------------------------------------------
// Pipeline (conv∘alpha = alpha∘conv, both linear, disjoint axes):
//   xT = transpose(x) as u8          [t*NB+n][c][h][w]   (x is binary spikes)
//   v1 = conv1(xT)                   f32 t-major
//   s1 = LIF1(alpha1(v1))  as u8
//   v2 = conv2(s1)                   f32 t-major
//   out = LIF2(alpha2(v2))           t-minor [n][c][h][w][t]
// ---------------------------------------------------------------------------

// K0: transpose x [n,c,h,w,t] f32(binary) -> xT [t*NB+n][c][h][w] u8.
__global__ __launch_bounds__(256) void k_tr(const float* __restrict__ x,
                                            unsigned char* __restrict__ xT) {
    __shared__ unsigned char lds[256 * 68];          // [e][68B] pad: 17 words/row
    const int tid = threadIdx.x;
    const size_t e0 = (size_t)blockIdx.x * 256;
    const float4* xb = reinterpret_cast<const float4*>(x + (e0 + tid) * TN);
    unsigned int* lds32 = reinterpret_cast<unsigned int*>(lds);
    #pragma unroll
    for (int k = 0; k < 16; ++k) {
        float4 v = xb[k];
        unsigned int p = ((unsigned)v.x) | (((unsigned)v.y) << 8) |
                         (((unsigned)v.z) << 16) | (((unsigned)v.w) << 24);
        lds32[tid * 17 + k] = p;                     // bank stride 17: conflict-free
    }
    __syncthreads();
    const int lane = tid & 63, w = tid >> 6;
    #pragma unroll
    for (int k = 0; k < 16; ++k) {
        int t = w * 16 + k;
        unsigned int b0 = lds[(4 * lane + 0) * 68 + t];
        unsigned int b1 = lds[(4 * lane + 1) * 68 + t];
        unsigned int b2 = lds[(4 * lane + 2) * 68 + t];
        unsigned int b3 = lds[(4 * lane + 3) * 68 + t];
        unsigned int p = b0 | (b1 << 8) | (b2 << 16) | (b3 << 24);
        *reinterpret_cast<unsigned int*>(xT + (size_t)t * NCHW + e0 + 4 * lane) = p;
    }
}

// ---------------------------------------------------------------------------
// K1: conv1 5x5 pad=2 on u8 input. WHOLE 8-channel tile as u8 in LDS
// ([8][12][136] = 13.1 KB) staged once -> ONE barrier per block; the entire
// 6400-FMA loop then runs sync-free (compiler pipelines ds_reads across ci).
// u8->f32 on read via v_cvt_f32_ubyte (320 ops, 5% of FMA). SMEM weights.
// ---------------------------------------------------------------------------
__global__ __launch_bounds__(256, 4) void k_conv1(const unsigned char* __restrict__ in,
                                                  const float* __restrict__ w1,
                                                  float* __restrict__ outp) {
    __shared__ __align__(16) unsigned char lds8[CH * 12 * 136];   // 13056 B
    const int img = blockIdx.y;                 // t*NB + n, 0..127
    const int h0 = blockIdx.x * 8;              // 16 y-tiles
    const int tid = threadIdx.x;
    const int yi = tid >> 5;                    // 0..7
    const int x0 = (tid & 31) * 4;              // 0..124
    const unsigned char* base = in + (size_t)img * CHW;

    // staging offsets: computed ONCE, reused for all 8 channels
    int goff[7];                                // 12*136 = 1632 slots/channel
    #pragma unroll
    for (int k = 0; k < 7; ++k) {
        int idx = tid + (k << 8);
        int r = idx / 136;
        int c = idx - r * 136;
        int gh = h0 + r - 2, gw = c - 2;
        bool ok = (idx < 1632) && (gh >= 0) && (gh < HH) && (gw >= 0) && (gw < WW);
        goff[k] = ok ? (gh * WW + gw) : -1;
    }

    #pragma unroll
    for (int ci = 0; ci < CH; ++ci) {
        const unsigned char* cb = base + ci * HW;
        #pragma unroll
        for (int k = 0; k < 7; ++k) {
            int idx = tid + (k << 8);
            if (k < 6 || idx < 1632) {
                int g = goff[k];
                int gc = g < 0 ? 0 : g;
                unsigned char v = cb[gc];
                lds8[ci * 1632 + idx] = (g < 0) ? (unsigned char)0 : v;
            }
        }
    }
    __syncthreads();                            // the ONLY barrier

    float acc[CH][4];
    #pragma unroll
    for (int co = 0; co < CH; ++co)
        #pragma unroll
        for (int xo = 0; xo < 4; ++xo) acc[co][xo] = 0.f;

    for (int ci = 0; ci < CH; ++ci) {           // dynamic: keeps code size sane
        const unsigned char* cp = lds8 + ci * 1632;
        #pragma unroll
        for (int ky = 0; ky < 5; ++ky) {
            const unsigned int* p =
                reinterpret_cast<const unsigned int*>(cp + (yi + ky) * 136 + x0);
            unsigned int a = p[0], b = p[1];
            float f[8] = {(float)(a & 0xff), (float)((a >> 8) & 0xff),
                          (float)((a >> 16) & 0xff), (float)(a >> 24),
                          (float)(b & 0xff), (float)((b >> 8) & 0xff),
                          (float)((b >> 16) & 0xff), (float)(b >> 24)};
            #pragma unroll
            for (int co = 0; co < CH; ++co) {
                const float* wp = w1 + (co * CH + ci) * 25 + ky * 5;
                #pragma unroll
                for (int kx = 0; kx < 5; ++kx) {
                    float wv = wp[kx];
                    #pragma unroll
                    for (int xo = 0; xo < 4; ++xo)
                        acc[co][xo] = fmaf(wv, f[kx + xo], acc[co][xo]);
                }
            }
        }
    }

    float* ob = outp + (size_t)img * CHW + (h0 + yi) * WW + x0;
    #pragma unroll
    for (int co = 0; co < CH; ++co)
        *reinterpret_cast<float4*>(ob + co * HW) =
            make_float4(acc[co][0], acc[co][1], acc[co][2], acc[co][3]);
}

// ---------------------------------------------------------------------------
// K2: fused alpha1 (tau=1) + LIF1 (theta=30, tauRef=1) -> s1 u8.
// ---------------------------------------------------------------------------
__global__ __launch_bounds__(256) void k_alif1(const float* __restrict__ v1,
                                               unsigned char* __restrict__ s1) {
    int e2 = blockIdx.x * blockDim.x + threadIdx.x;   // 0..NCHW/2-1
    if (e2 >= NCHW / 2) return;
    const float d1 = 0.36787944117144233f;  // exp(-1)
    const float c1 = 2.7182818284590452f;   // e
    const float dr = 0.36787944117144233f;  // exp(-1)
    const float rg = 81.54845485377136f;    // 30*e
    const float th = 30.f;
    float P0 = 0.f, Q0 = 0.f, Pr0 = 0.f, Qr0 = 0.f;
    float P1 = 0.f, Q1 = 0.f, Pr1 = 0.f, Qr1 = 0.f;
    const float2* ve = reinterpret_cast<const float2*>(v1);
    #pragma unroll 8
    for (int t = 0; t < TN; ++t) {
        float2 v = ve[(size_t)t * (NCHW / 2) + e2];
        Q0 = d1 * (Q0 + P0); P0 = d1 * P0 + v.x;
        Qr0 = dr * (Qr0 + Pr0);
        float s0 = (c1 * Q0 - rg * Qr0 >= th) ? 1.0f : 0.0f;
        Pr0 = dr * Pr0 + s0;
        Q1 = d1 * (Q1 + P1); P1 = d1 * P1 + v.y;
        Qr1 = dr * (Qr1 + Pr1);
        float s1v = (c1 * Q1 - rg * Qr1 >= th) ? 1.0f : 0.0f;
        Pr1 = dr * Pr1 + s1v;
        uchar2 o; o.x = (unsigned char)s0; o.y = (unsigned char)s1v;
        *reinterpret_cast<uchar2*>(s1 + (size_t)t * NCHW + 2 * e2) = o;
    }
}

// ---------------------------------------------------------------------------
// K3: conv2 3x3 pad=1 on u8 spikes. Same one-barrier u8-tile structure.
// LDS [8][10][136] u8 = 10.9 KB.
// ---------------------------------------------------------------------------
__global__ __launch_bounds__(256, 4) void k_conv2(const unsigned char* __restrict__ in,
                                                  const float* __restrict__ w2,
                                                  float* __restrict__ outp) {
    __shared__ __align__(16) unsigned char lds8[CH * 10 * 136];   // 10880 B
    const int img = blockIdx.y;
    const int h0 = blockIdx.x * 8;
    const int tid = threadIdx.x;
    const int yi = tid >> 5;
    const int x0 = (tid & 31) * 4;
    const unsigned char* base = in + (size_t)img * CHW;

    int goff[6];                                // 10*136 = 1360 slots/channel
    #pragma unroll
    for (int k = 0; k < 6; ++k) {
        int idx = tid + (k << 8);
        int r = idx / 136;
        int c = idx - r * 136;
        int gh = h0 + r - 1, gw = c - 1;
        bool ok = (idx < 1360) && (gh >= 0) && (gh < HH) && (gw >= 0) && (gw < WW);
        goff[k] = ok ? (gh * WW + gw) : -1;
    }

    #pragma unroll
    for (int ci = 0; ci < CH; ++ci) {
        const unsigned char* cb = base + ci * HW;
        #pragma unroll
        for (int k = 0; k < 6; ++k) {
            int idx = tid + (k << 8);
            if (k < 5 || idx < 1360) {
                int g = goff[k];
                int gc = g < 0 ? 0 : g;
                unsigned char v = cb[gc];
                lds8[ci * 1360 + idx] = (g < 0) ? (unsigned char)0 : v;
            }
        }
    }
    __syncthreads();                            // the ONLY barrier

    float acc[CH][4];
    #pragma unroll
    for (int co = 0; co < CH; ++co)
        #pragma unroll
        for (int xo = 0; xo < 4; ++xo) acc[co][xo] = 0.f;

    for (int ci = 0; ci < CH; ++ci) {
        const unsigned char* cp = lds8 + ci * 1360;
        #pragma unroll
        for (int ky = 0; ky < 3; ++ky) {
            const unsigned int* p =
                reinterpret_cast<const unsigned int*>(cp + (yi + ky) * 136 + x0);
            unsigned int a = p[0], b = p[1];
            float f[8] = {(float)(a & 0xff), (float)((a >> 8) & 0xff),
                          (float)((a >> 16) & 0xff), (float)(a >> 24),
                          (float)(b & 0xff), (float)((b >> 8) & 0xff),
                          (float)((b >> 16) & 0xff), (float)(b >> 24)};
            #pragma unroll
            for (int co = 0; co < CH; ++co) {
                const float* wp = w2 + (co * CH + ci) * 9 + ky * 3;
                #pragma unroll
                for (int kx = 0; kx < 3; ++kx) {
                    float wv = wp[kx];
                    #pragma unroll
                    for (int xo = 0; xo < 4; ++xo)
                        acc[co][xo] = fmaf(wv, f[kx + xo], acc[co][xo]);
                }
            }
        }
    }

    float* ob = outp + (size_t)img * CHW + (h0 + yi) * WW + x0;
    #pragma unroll
    for (int co = 0; co < CH; ++co)
        *reinterpret_cast<float4*>(ob + co * HW) =
            make_float4(acc[co][0], acc[co][1], acc[co][2], acc[co][3]);
}

// ---------------------------------------------------------------------------
// K4: fused alpha2 (tau=2) + LIF2 (theta=50, tauRef=2), t-minor f32 output.
// ---------------------------------------------------------------------------
__global__ __launch_bounds__(256) void k_alif2(const float* __restrict__ v2,
                                               float* __restrict__ outp) {
    int e = blockIdx.x * blockDim.x + threadIdx.x;
    if (e >= NCHW) return;
    const float d2 = 0.60653065971263342f;  // exp(-0.5)
    const float c2 = 1.35914091422952262f;  // e/2
    const float dr = 0.60653065971263342f;  // exp(-0.5)
    const float rg = 67.95704571147613f;    // 25*e
    const float th = 50.f;
    float P = 0.f, Q = 0.f, Pr = 0.f, Qr = 0.f;
    float sv[TN];
    #pragma unroll
    for (int t = 0; t < TN; ++t) {
        Q = d2 * (Q + P);
        P = d2 * P + v2[(size_t)t * NCHW + e];
        Qr = dr * (Qr + Pr);
        float s = (c2 * Q - rg * Qr >= th) ? 1.0f : 0.0f;
        Pr = dr * Pr + s;
        sv[t] = s;
    }
    float4* o = reinterpret_cast<float4*>(outp + (size_t)e * TN);
    #pragma unroll
    for (int i = 0; i < TN / 4; ++i)
        o[i] = make_float4(sv[4 * i], sv[4 * i + 1], sv[4 * i + 2], sv[4 * i + 3]);
}

// ---------------------------------------------------------------------------
extern "C" void kernel_launch(void* const* d_in, const int* in_sizes, int n_in,
                              void* d_out, int out_size, void* d_ws, size_t ws_size,
                              hipStream_t stream) {
    const float* x  = (const float*)d_in[0];   // [2,8,128,128,64] binary
    const float* w1 = (const float*)d_in[1];   // [8,8,5,5]
    const float* w2 = (const float*)d_in[2];   // [8,8,3,3]
    float* out = (float*)d_out;                // [2,8,128,128,64]

    // workspace: v-buffer f32 64MB (v1 then v2) + xT u8 16MB + s1 u8 16MB
    float* vbuf = (float*)d_ws;
    unsigned char* xT = (unsigned char*)d_ws + (size_t)TN * NCHW * 4;
    unsigned char* s1 = xT + (size_t)TN * NCHW;

    dim3 blk(256);
    dim3 grd_pt(NCHW / 256);          // 1024 blocks
    dim3 grd_pt2(NCHW / 512);         // 512 blocks (float2 kernel)
    dim3 grd_cv(16, TN * NB);         // 16 row-tiles x 128 images

    k_tr<<<grd_pt, blk, 0, stream>>>(x, xT);
    k_conv1<<<grd_cv, blk, 0, stream>>>(xT, w1, vbuf);
    k_alif1<<<grd_pt2, blk, 0, stream>>>(vbuf, s1);
    k_conv2<<<grd_cv, blk, 0, stream>>>(s1, w2, vbuf);
    k_alif2<<<grd_pt, blk, 0, stream>>>(vbuf, out);
}